// Round 10
// baseline (162.348 us; speedup 1.0000x reference)
//
#include <hip/hip_runtime.h>
#include <hip/hip_bf16.h>

// SConv2dAvg: stride-2 conv with per-output-pixel stochastic tap selection.
// B=32 C=128 H=W=64, O=256 kh=kw=3, oh=ow=32, PAD=1, STRIDE=2.
//
// Round 10 structure:
//  prep (fused): weight fp32 -> bf16 wpre[36][256][4pos][8] (K-step 32,
//    chunk-pos XOR (o&3) baked); input NCHW fp32 -> bf16 padded NHWC
//    tp[32][66][66][128] (zero halo).
//  sconv_mfma10: block = 256o x 128pix (A read exactly once — minimal
//    combined A+B traffic at grid 256), 512 thr / 8 waves (4o x 2p of 64x64),
//    K-step 32, 36 steps. LDS 2-buf (A 8K + B 16K) = 49.6 KB -> 3 blocks/CU,
//    24 waves/CU (R4-class concurrency; R9's 1 block/CU was the regression).
//    R3/R4-proven sync: K-loop vmem = global_load_lds ONLY, exact vmcnt(3),
//    1-step prefetch, 2 barriers/step. XCD-chunked swizzle (T1), setprio (T5).

typedef short bf16x8 __attribute__((ext_vector_type(8)));
typedef float f32x4  __attribute__((ext_vector_type(4)));

#define WPRE_BYTES (36 * 256 * 32 * 2)              // 589824
#define TRANS_BYTES (32 * 66 * 66 * 128 * 2)        // 35684352
#define TOTAL_WS (WPRE_BYTES + TRANS_BYTES)

__device__ __forceinline__ unsigned short f2bf(float x) {
  unsigned u = __float_as_uint(x);
  return (unsigned short)((u + 0x7fffu + ((u >> 16) & 1u)) >> 16);
}
__device__ __forceinline__ unsigned pk2(float a, float b) {
  unsigned ua = __float_as_uint(a), ub = __float_as_uint(b);
  return ((ua + 0x7fffu + ((ua >> 16) & 1u)) >> 16) |
         ((ub + 0x7fffu + ((ub >> 16) & 1u)) & 0xffff0000u);
}
__device__ __forceinline__ bf16x8 ld_frag(const uint4* a) {
  union { uint4 u; bf16x8 s; } cv; cv.u = *a; return cv.s;
}
__device__ __forceinline__ void async16(const void* g, void* l) {
  __builtin_amdgcn_global_load_lds(
      (__attribute__((address_space(1))) void*)(void*)g,
      (__attribute__((address_space(3))) void*)l, 16, 0, 0);
}

// ---------------- fused pre-pass: transform + wprep ------------------------
// grid (102, 32): x < 66 -> padded-NHWC transform of (row hp=x, batch y);
//                 x >= 66 -> wprep: linear elem L = ((x-66)*32+y)*256+tid.
__global__ __launch_bounds__(256) void prep(const float* __restrict__ in,
                                            const float* __restrict__ w,
                                            unsigned short* __restrict__ tp,
                                            unsigned short* __restrict__ wpre) {
  const int tid = threadIdx.x;
  if (blockIdx.x >= 66) {
    // wpre[s][o][pos][e] = W[o][ c=(s&3)*32 + (pos^(o&3))*8 + e ][ tap=s>>2 ]
    const int L   = ((((blockIdx.x - 66) << 5) + blockIdx.y) << 8) + tid;
    const int e   = L & 7;
    const int pos = (L >> 3) & 3;
    const int o   = (L >> 5) & 255;
    const int s   = L >> 13;                        // 0..35
    const int c   = ((s & 3) << 5) + ((pos ^ (o & 3)) << 3) + e;
    wpre[L] = f2bf(w[(o * 128 + c) * 9 + (s >> 2)]);
    return;
  }
  // ---- input transform ----
  __shared__ float lds[128 * 65];
  const int hp = blockIdx.x;   // 0..65 padded row
  const int b  = blockIdx.y;
  uint4* rowp = (uint4*)(tp + (size_t)(b * 66 + hp) * 66 * 128);
  uint4 z; z.x = z.y = z.z = z.w = 0u;
  if (hp == 0 || hp == 65) {                 // zero border rows
    for (int s = tid; s < 1056; s += 256) rowp[s] = z;
    return;
  }
  const int h = hp - 1;
  const float* src = in + ((size_t)b << 19) + (h << 6);
  const int ww4 = (tid & 15) << 2;
  const int c0  = tid >> 4;
#pragma unroll
  for (int pass = 0; pass < 8; ++pass) {
    int c = (pass << 4) + c0;
    float4 v = *(const float4*)(src + ((size_t)c << 12) + ww4);  // coalesced
    float* lp = lds + c * 65 + ww4;
    lp[0] = v.x; lp[1] = v.y; lp[2] = v.z; lp[3] = v.w;
  }
  __syncthreads();
  for (int s = tid; s < 1056; s += 256) {
    if (s < 16 || s >= 1040) { rowp[s] = z; continue; }   // zero border cols
    int idx = s - 16;
    int wq = idx >> 4, c8 = idx & 15;
    const float* lp = lds + (c8 << 3) * 65 + wq;
    uint4 d;
    d.x = pk2(lp[0],   lp[65]);
    d.y = pk2(lp[130], lp[195]);
    d.z = pk2(lp[260], lp[325]);
    d.w = pk2(lp[390], lp[455]);
    rowp[s] = d;
  }
}

// ----------------------------- main kernel ---------------------------------
// LDS layouts (uint4 units):
//   Alds[buf][p*4 + chunk]  — chunk holds SOURCE chunk (chunk ^ (p&3)), i.e.
//     the XOR is folded into the per-lane global source address (rule #21).
//   Blds[buf][o*4 + pos]    — pos holds chunk pos^(o&3) (baked in wpre).
// Reads: FW = B[O*4 + (hi^(O&3))], FP = A[P*4 + (hi^(P&3))] — 2-way max
// bank aliasing (free, m136).
__global__ __launch_bounds__(512, 6) void sconv_mfma10(
    const unsigned short* __restrict__ tp,   // [32][66][66][128] bf16 padded
    const unsigned short* __restrict__ wpre, // [36][256][32] bf16 pre-swizzled
    const float* __restrict__ bias,
    const int* __restrict__ selh,            // [32][32]
    const int* __restrict__ selw,            // [32][32]
    float* __restrict__ out)                 // [32][256][32][32]
{
  __shared__ uint4 Alds[2][512];    // patches: 8KB/buf
  __shared__ uint4 Blds[2][1024];   // weights: 16KB/buf
  __shared__ float bias_s[256];

  const int tid = threadIdx.x;
  // XCD-chunked swizzle (T1): 256 = 8 XCDs x 32 consecutive logical blocks
  const int d0  = blockIdx.x;
  const int blk = ((d0 & 7) << 5) | (d0 >> 3);
  const int b   = blk >> 3;                 // batch
  const int y0  = (blk & 7) << 2;           // 4 output rows

  if (tid < 256) bias_s[tid] = bias[tid];

  const int wv = tid >> 6, ln = tid & 63;
  const int lo = ln & 15, hi = ln >> 4;

  // ---- A staging role: thread owns pixel p = tid>>2, chunk q = tid&3
  const int p = tid >> 2;
  const int q = tid & 3;
  int asrc;                         // byte offset of pixel row at tap (0,0)
  {
    const int py = y0 + (p >> 5), px = p & 31;
    asrc = (((b * 66 + 2 * py + selh[(py << 5) | px]) * 66
             + 2 * px + selw[(py << 5) | px]) << 8) + ((q ^ (p & 3)) << 4);
  }
  const char* tbase = (const char*)tp;
  // B staging: fully linear (swizzle baked in wpre); 16KB/step, 2 instrs/thr
  const char* wsrc = (const char*)wpre + (tid << 4);

  // ---- MFMA role: wave (wo,wp) owns 64o x 64pix
  const int wo = wv >> 1;           // 4 o-waves x 64 o
  const int wp = wv & 1;            // 2 p-waves x 64 pix

  f32x4 acc[4][4] = {};             // [o-frag][pix-frag]

#define STAGE(BUF, T)                                                         \
  do {                                                                        \
    const int tap_ = (T) >> 2;                                                \
    const int di_  = (tap_ >= 6) ? 2 : ((tap_ >= 3) ? 1 : 0);                 \
    const int dj_  = tap_ - 3 * di_;                                          \
    /* A: 1 instr/thread, per-lane source, linear LDS dest */                 \
    async16(tbase + asrc + ((di_ * 66 + dj_) << 8) + (((T) & 3) << 6),        \
            &Alds[BUF][(wv << 6)]);                                           \
    /* B: 2 instrs/thread, linear 16KB */                                     \
    async16(wsrc + ((T) << 14),        &Blds[BUF][(wv << 6)]);                \
    async16(wsrc + ((T) << 14) + 8192, &Blds[BUF][(wv << 6) + 512]);          \
  } while (0)

#define COMPUTE(BUF)                                                         \
  do {                                                                       \
    const uint4* A_ = &Alds[BUF][0];                                         \
    const uint4* B_ = &Blds[BUF][0];                                         \
    bf16x8 FW[4], FP[4];                                                     \
    _Pragma("unroll")                                                        \
    for (int f = 0; f < 4; ++f) {                                            \
      const int O = (wo << 6) + (f << 4) + lo;                               \
      const int P = (wp << 6) + (f << 4) + lo;                               \
      FW[f] = ld_frag(B_ + (O << 2) + (hi ^ (O & 3)));                       \
      FP[f] = ld_frag(A_ + (P << 2) + (hi ^ (P & 3)));                       \
    }                                                                        \
    __builtin_amdgcn_s_setprio(1);                                           \
    _Pragma("unroll")                                                        \
    for (int fo = 0; fo < 4; ++fo)                                           \
      _Pragma("unroll")                                                      \
      for (int fp = 0; fp < 4; ++fp)                                         \
        acc[fo][fp] = __builtin_amdgcn_mfma_f32_16x16x32_bf16(               \
            FW[fo], FP[fp], acc[fo][fp], 0, 0, 0);                           \
    __builtin_amdgcn_s_setprio(0);                                           \
  } while (0)

  // drain setup loads (sel/bias) so the counted vmcnt below is exact
  asm volatile("s_waitcnt vmcnt(0) lgkmcnt(0)" ::: "memory");
  __builtin_amdgcn_s_barrier();
  asm volatile("" ::: "memory");

  STAGE(0, 0);                      // prologue: 3 loads in flight

#pragma unroll 4
  for (int t = 0; t < 35; ++t) {
    STAGE((t + 1) & 1, t + 1);                         // 1-step prefetch
    asm volatile("s_waitcnt vmcnt(3)" ::: "memory");   // step-t loads landed
    __builtin_amdgcn_s_barrier();          // all waves' buf[t&1] complete
    asm volatile("" ::: "memory");
    COMPUTE(t & 1);                        // 8 ds_read_b128 + 16 MFMA
    asm volatile("s_waitcnt lgkmcnt(0)" ::: "memory");   // reads retired
    __builtin_amdgcn_s_barrier();          // before buf[t&1] is overwritten
    asm volatile("" ::: "memory");
  }
  asm volatile("s_waitcnt vmcnt(0)" ::: "memory");     // step 35
  __builtin_amdgcn_s_barrier();
  asm volatile("" ::: "memory");
  COMPUTE(1);
#undef STAGE
#undef COMPUTE

  // ---- epilogue: D row = o (hi*4+j), col = pix (lo); +bias
  float* ob = out + ((size_t)b << 18) + (y0 << 5);
#pragma unroll
  for (int fo = 0; fo < 4; ++fo) {
    const int obase = (wo << 6) + (fo << 4) + (hi << 2);
#pragma unroll
    for (int fp = 0; fp < 4; ++fp) {
      const int P = (wp << 6) + (fp << 4) + lo;
#pragma unroll
      for (int j = 0; j < 4; ++j) {
        const int o = obase + j;
        ob[((size_t)o << 10) + P] = acc[fo][fp][j] + bias_s[o];
      }
    }
  }
}

// ------------------- exact fp32 fallback (ws too small) --------------------
__global__ __launch_bounds__(256) void sconv_naive(
    const float* __restrict__ in, const float* __restrict__ w,
    const float* __restrict__ bias, const int* __restrict__ selh,
    const int* __restrict__ selw, float* __restrict__ out) {
  int idx = (blockIdx.x << 8) + threadIdx.x;
  if (idx >= 32 * 256 * 32 * 32) return;
  int x = idx & 31, y = (idx >> 5) & 31, o = (idx >> 10) & 255, b = idx >> 18;
  int rh0 = 2 * y + selh[(y << 5) | x] - 1;
  int rw0 = 2 * x + selw[(y << 5) | x] - 1;
  const float* inb = in + ((size_t)b << 19);
  const float* wo_ = w + o * 1152;
  float acc = bias[o];
  for (int c = 0; c < 128; ++c)
    for (int i = 0; i < 3; ++i) {
      int rh = rh0 + i;
      if (rh < 0 || rh >= 64) continue;
      for (int j = 0; j < 3; ++j) {
        int rw = rw0 + j;
        if (rw < 0 || rw >= 64) continue;
        acc += inb[(c << 12) + (rh << 6) + rw] * wo_[c * 9 + i * 3 + j];
      }
    }
  out[idx] = acc;
}

extern "C" void kernel_launch(void* const* d_in, const int* in_sizes, int n_in,
                              void* d_out, int out_size, void* d_ws, size_t ws_size,
                              hipStream_t stream) {
  const float* in   = (const float*)d_in[0];
  const float* w    = (const float*)d_in[1];
  const float* bias = (const float*)d_in[2];
  const int*   selh = (const int*)d_in[3];
  const int*   selw = (const int*)d_in[4];
  float* out = (float*)d_out;

  if (ws_size >= (size_t)TOTAL_WS) {
    unsigned short* wpre = (unsigned short*)d_ws;
    unsigned short* tp   = (unsigned short*)((char*)d_ws + WPRE_BYTES);
    prep<<<dim3(102, 32), dim3(256), 0, stream>>>(in, w, tp, wpre);
    sconv_mfma10<<<dim3(256), dim3(512), 0, stream>>>(tp, wpre, bias, selh, selw, out);
  } else {
    sconv_naive<<<dim3(32768), dim3(256), 0, stream>>>(in, w, bias, selh, selw, out);
  }
}

// Round 11
// 45.475 us; speedup vs baseline: 3.5700x; 3.5700x over previous
//
#include <hip/hip_runtime.h>
#include <hip/hip_bf16.h>

// SConv2dAvg: stride-2 conv with per-output-pixel stochastic tap selection.
// B=32 C=128 H=W=64, O=256 kh=kw=3, oh=ow=32, PAD=1, STRIDE=2.
//
// Round 11 — FUSED design (no tp materialization):
//  wprep: fp32 weights -> bf16 wq[8cc][5pair][256o][4chunk][8], tap-pairs
//    (k-unit 32 = 2 taps x 16 c), tap 9 zero-padded, FW chunk-XOR (o&3) baked.
//  sconv_fused: grid 256 (b x 4-row group, 1 blk/CU), 512 thr / 8 waves
//    (4 o-waves x 2 p-waves of 64x64). Per c-chunk (16 ch): stage a 10-row
//    input slab NCHW->LDS with in-LDS transpose to [row][col][c] bf16 —
//    the sel-gather becomes LDS addressing (sel-independent global reads!).
//    Input read once (+22% halo). 2 __syncthreads per phase; NO counted
//    vmcnt, NO global_load_lds (R7/R10 lessons) — compiler owns all waits.
//    __launch_bounds__(512,2): 256-reg budget, no spill possible.

typedef short bf16x8 __attribute__((ext_vector_type(8)));
typedef float f32x4  __attribute__((ext_vector_type(4)));

#define WQ_BYTES (40 * 256 * 64)    // 655360

__device__ __forceinline__ unsigned short f2bf(float x) {
  unsigned u = __float_as_uint(x);
  return (unsigned short)((u + 0x7fffu + ((u >> 16) & 1u)) >> 16);
}
__device__ __forceinline__ unsigned pk2(float a, float b) {
  unsigned ua = __float_as_uint(a), ub = __float_as_uint(b);
  return ((ua + 0x7fffu + ((ua >> 16) & 1u)) >> 16) |
         ((ub + 0x7fffu + ((ub >> 16) & 1u)) & 0xffff0000u);
}
__device__ __forceinline__ bf16x8 ld_frag(const uint4* a) {
  union { uint4 u; bf16x8 s; } cv; cv.u = *a; return cv.s;
}

// ---- weight repack: wq[t5=cc*5+pair][o][hst][e], content hi = hst^(o&3) ----
__global__ __launch_bounds__(256) void wprep(const float* __restrict__ w,
                                             unsigned short* __restrict__ wq) {
  const int L   = (blockIdx.x << 8) + threadIdx.x;   // 0..655359
  const int e   = L & 7;
  const int hst = (L >> 3) & 3;
  const int o   = (L >> 5) & 255;
  const int t5  = L >> 13;                 // 0..39
  const int cc  = t5 / 5, pair = t5 - 5 * cc;
  const int hi  = hst ^ (o & 3);
  const int tap = 2 * pair + (hi >> 1);
  const int c   = (cc << 4) + ((hi & 1) << 3) + e;
  wq[L] = (tap <= 8) ? f2bf(w[(o * 128 + c) * 9 + tap]) : (unsigned short)0;
}

// ----------------------------- fused main ----------------------------------
__global__ __launch_bounds__(512, 2) void sconv_fused(
    const float* __restrict__ in,            // [32][128][64][64] fp32
    const unsigned short* __restrict__ wq,   // 655360 B, pre-packed
    const float* __restrict__ bias,
    const int* __restrict__ selh,            // [32][32]
    const int* __restrict__ selw,            // [32][32]
    float* __restrict__ out)                 // [32][256][32][32]
{
  __shared__ uint4 Bbuf[5120];      // 80 KB: one c-chunk of weights
  __shared__ uint4 slab[2][1320];   // 2 x 20.6 KB: [r2=row*2+chalf][col' 66]
  __shared__ uint4 scratch[1280];   // 20 KB: bf16 [r10][c16][w64]
  __shared__ float bias_s[256];

  const int tid = threadIdx.x;
  const int d0  = blockIdx.x;                 // XCD swizzle (harmless at 1/CU)
  const int blk = ((d0 & 7) << 5) | (d0 >> 3);
  const int b   = blk >> 3;
  const int y0  = (blk & 7) << 2;             // 4 output rows

  if (tid < 256) bias_s[tid] = bias[tid];

  const int wv = tid >> 6, ln = tid & 63;
  const int lo = ln & 15, hi = ln >> 4;
  const int wo = wv >> 1, wp = wv & 1;        // 4 o-waves x 2 p-waves (64x64)
  const int h2 = hi >> 1, ch = hi & 1;        // tap-in-pair, c-half

  // per-frag pixel constants (sel folded into LDS addressing)
  int pr[4], pc[4];
#pragma unroll
  for (int f = 0; f < 4; ++f) {
    const int pxl = (wp << 6) + (f << 4) + lo;     // 0..127
    const int py  = y0 + (pxl >> 5), px = pxl & 31;
    pr[f] = ((pxl >> 5) << 1) + selh[(py << 5) | px];   // 0..7
    pc[f] = (px << 1) + selw[(py << 5) | px];           // 0..63
  }
  const float* inb = in + ((size_t)b << 19);
  const int fwswz = hi ^ (lo & 3);
  int Obase[4];
#pragma unroll
  for (int fo = 0; fo < 4; ++fo)
    Obase[fo] = (((wo << 6) + (fo << 4) + lo) << 2) + fwswz;

  f32x4 acc[4][4] = {};
  float4 ar[5]; uint4 br[10];
  const float4 z4 = make_float4(0.f, 0.f, 0.f, 0.f);

#define LOAD_A(CC)                                                            \
  do {                                                                        \
    _Pragma("unroll")                                                         \
    for (int i = 0; i < 5; ++i) {                                             \
      const int q = tid + (i << 9);          /* 2560 quads */                 \
      const int c = ((CC) << 4) + ((q >> 4) & 15);                            \
      const int h = (y0 << 1) - 1 + (q >> 8);                                 \
      ar[i] = (h >= 0 && h < 64)                                              \
          ? *(const float4*)(inb + ((size_t)c << 12) + (h << 6) + ((q & 15) << 2)) \
          : z4;                                                               \
    }                                                                         \
  } while (0)

#define WRITE_SCRATCH()                                                       \
  do {                                                                        \
    _Pragma("unroll")                                                         \
    for (int i = 0; i < 5; ++i) {                                             \
      const int q = tid + (i << 9);                                           \
      uint2 d2; d2.x = pk2(ar[i].x, ar[i].y); d2.y = pk2(ar[i].z, ar[i].w);   \
      *(uint2*)((char*)scratch + q * 8) = d2;                                 \
    }                                                                         \
  } while (0)

  // scratch bf16 [r][c16][w]: transpose-read 8 c's for a w-pair -> 2 cells
#define PASS2(DST)                                                            \
  do {                                                                        \
    _Pragma("unroll")                                                         \
    for (int rep = 0; rep < 2; ++rep) {                                       \
      const int s2 = tid + (rep << 9);                                        \
      if (s2 < 640) {                                                         \
        const int r = s2 >> 6, rem = s2 & 63;                                 \
        const int chp = rem >> 5, w2 = rem & 31;                              \
        unsigned u[8];                                                        \
        _Pragma("unroll")                                                     \
        for (int i = 0; i < 8; ++i)                                           \
          u[i] = *(const unsigned*)((const char*)scratch +                    \
                   ((r << 4) + (chp << 3) + i) * 128 + (w2 << 2));            \
        uint4 ev, od;                                                         \
        ev.x = (u[0] & 0xffffu) | (u[1] << 16);                               \
        ev.y = (u[2] & 0xffffu) | (u[3] << 16);                               \
        ev.z = (u[4] & 0xffffu) | (u[5] << 16);                               \
        ev.w = (u[6] & 0xffffu) | (u[7] << 16);                               \
        od.x = (u[0] >> 16) | (u[1] & 0xffff0000u);                           \
        od.y = (u[2] >> 16) | (u[3] & 0xffff0000u);                           \
        od.z = (u[4] >> 16) | (u[5] & 0xffff0000u);                           \
        od.w = (u[6] >> 16) | (u[7] & 0xffff0000u);                           \
        const int r2 = ((r << 1) + chp) * 66;                                 \
        slab[DST][r2 + w2 + 33] = ev;   /* col=2w2+1 (odd)  -> col'=w2+33 */  \
        slab[DST][r2 + w2 + 1]  = od;   /* col=2w2+2 (even) -> col'=w2+1  */  \
      }                                                                       \
    }                                                                         \
    if (tid < 40) {                        /* halo cols 0 and 65 -> zero */   \
      uint4 zz; zz.x = zz.y = zz.z = zz.w = 0u;                               \
      slab[DST][(tid >> 1) * 66 + ((tid & 1) ? 65 : 0)] = zz;                 \
    }                                                                         \
  } while (0)

#define LOAD_B(CC)                                                            \
  do {                                                                        \
    _Pragma("unroll")                                                         \
    for (int i = 0; i < 10; ++i)                                              \
      br[i] = *(const uint4*)((const char*)wq + (CC) * 81920 +                \
                              ((tid + (i << 9)) << 4));                       \
  } while (0)

#define WRITE_B()                                                             \
  do {                                                                        \
    _Pragma("unroll")                                                         \
    for (int i = 0; i < 10; ++i) Bbuf[tid + (i << 9)] = br[i];                \
  } while (0)

#define COMPUTE(SB)                                                           \
  do {                                                                        \
    _Pragma("unroll")                                                         \
    for (int pair = 0; pair < 5; ++pair) {                                    \
      bf16x8 FW[4], FP[4];                                                    \
      _Pragma("unroll")                                                       \
      for (int fo = 0; fo < 4; ++fo)                                          \
        FW[fo] = ld_frag(Bbuf + (pair << 10) + Obase[fo]);                    \
      int tap = (pair << 1) + h2; if (tap > 8) tap = 8;                       \
      const int di = (tap >= 6) ? 2 : ((tap >= 3) ? 1 : 0);                   \
      const int dj = tap - 3 * di;                                            \
      _Pragma("unroll")                                                       \
      for (int f = 0; f < 4; ++f) {                                           \
        const int col  = pc[f] + dj;                                          \
        const int colp = (col >> 1) + ((col & 1) ? 33 : 0);                   \
        FP[f] = ld_frag(&slab[SB][(((pr[f] + di) << 1) + ch) * 66 + colp]);   \
      }                                                                       \
      __builtin_amdgcn_s_setprio(1);                                          \
      _Pragma("unroll")                                                       \
      for (int fo = 0; fo < 4; ++fo)                                          \
        _Pragma("unroll")                                                     \
        for (int f = 0; f < 4; ++f)                                           \
          acc[fo][f] = __builtin_amdgcn_mfma_f32_16x16x32_bf16(               \
              FW[fo], FP[f], acc[fo][f], 0, 0, 0);                            \
      __builtin_amdgcn_s_setprio(0);                                          \
    }                                                                         \
  } while (0)

  // prologue: slab for chunk 0
  LOAD_A(0);
  WRITE_SCRATCH();
  __syncthreads();
  PASS2(0);
  __syncthreads();

  for (int cc = 0; cc < 8; ++cc) {
    LOAD_B(cc);
    if (cc < 7) LOAD_A(cc + 1);
    WRITE_B();
    __syncthreads();                 // Bbuf + slab[cc&1] published
    COMPUTE(cc & 1);
    if (cc < 7) WRITE_SCRATCH();
    __syncthreads();                 // scratch published; computes drained
    if (cc < 7) PASS2((cc + 1) & 1);
  }

  // ---- epilogue: D row = o (hi*4+j), col = pix (lo); +bias
  float* ob = out + ((size_t)b << 18) + (y0 << 5);
#pragma unroll
  for (int fo = 0; fo < 4; ++fo) {
    const int obase = (wo << 6) + (fo << 4) + (hi << 2);
#pragma unroll
    for (int f = 0; f < 4; ++f) {
      const int P = (wp << 6) + (f << 4) + lo;
#pragma unroll
      for (int j = 0; j < 4; ++j) {
        const int o = obase + j;
        ob[((size_t)o << 10) + P] = acc[fo][f][j] + bias_s[o];
      }
    }
  }
#undef LOAD_A
#undef WRITE_SCRATCH
#undef PASS2
#undef LOAD_B
#undef WRITE_B
#undef COMPUTE
}

// ------------------- exact fp32 fallback (ws too small) --------------------
__global__ __launch_bounds__(256) void sconv_naive(
    const float* __restrict__ in, const float* __restrict__ w,
    const float* __restrict__ bias, const int* __restrict__ selh,
    const int* __restrict__ selw, float* __restrict__ out) {
  int idx = (blockIdx.x << 8) + threadIdx.x;
  if (idx >= 32 * 256 * 32 * 32) return;
  int x = idx & 31, y = (idx >> 5) & 31, o = (idx >> 10) & 255, b = idx >> 18;
  int rh0 = 2 * y + selh[(y << 5) | x] - 1;
  int rw0 = 2 * x + selw[(y << 5) | x] - 1;
  const float* inb = in + ((size_t)b << 19);
  const float* wo_ = w + o * 1152;
  float acc = bias[o];
  for (int c = 0; c < 128; ++c)
    for (int i = 0; i < 3; ++i) {
      int rh = rh0 + i;
      if (rh < 0 || rh >= 64) continue;
      for (int j = 0; j < 3; ++j) {
        int rw = rw0 + j;
        if (rw < 0 || rw >= 64) continue;
        acc += inb[(c << 12) + (rh << 6) + rw] * wo_[c * 9 + i * 3 + j];
      }
    }
  out[idx] = acc;
}

extern "C" void kernel_launch(void* const* d_in, const int* in_sizes, int n_in,
                              void* d_out, int out_size, void* d_ws, size_t ws_size,
                              hipStream_t stream) {
  const float* in   = (const float*)d_in[0];
  const float* w    = (const float*)d_in[1];
  const float* bias = (const float*)d_in[2];
  const int*   selh = (const int*)d_in[3];
  const int*   selw = (const int*)d_in[4];
  float* out = (float*)d_out;

  if (ws_size >= (size_t)WQ_BYTES) {
    unsigned short* wq = (unsigned short*)d_ws;
    wprep<<<dim3(2560), dim3(256), 0, stream>>>(w, wq);
    sconv_fused<<<dim3(256), dim3(512), 0, stream>>>(in, wq, bias, selh, selw, out);
  } else {
    sconv_naive<<<dim3(32768), dim3(256), 0, stream>>>(in, w, bias, selh, selw, out);
  }
}